// Round 17
// baseline (375.887 us; speedup 1.0000x reference)
//
#include <hip/hip_runtime.h>

typedef unsigned short u16;
typedef __attribute__((ext_vector_type(8))) short short8v;
typedef __attribute__((ext_vector_type(4))) float f32x4;

#define P1_CHUNK 8192
#define BKCAP    4096   // fixed bucket capacity: mean fill 2046, ~45-sigma margin

__device__ __forceinline__ u16 f2b(float f) {
  union { float fv; unsigned int i; } v; v.fv = f;
  unsigned int x = v.i;
  return (u16)((x + 0x7FFFu + ((x >> 16) & 1u)) >> 16);
}
__device__ __forceinline__ float bs2f(u16 u) {
  union { unsigned i; float f; } v; v.i = (unsigned)u << 16; return v.f;
}
__device__ __forceinline__ float blo(unsigned u) {
  union { unsigned i; float f; } v; v.i = u << 16; return v.f;
}
__device__ __forceinline__ float bhi(unsigned u) {
  union { unsigned i; float f; } v; v.i = u & 0xFFFF0000u; return v.f;
}

// ---------------- weight + emb prep + gcur zeroing (one launch, coalesced
// global writes -- round-14 lesson: no strided ds_write transposes) ----------
__global__ __launch_bounds__(256) void k_prepw_all(
    const float* __restrict__ Wp, const float* __restrict__ W1a,
    const float* __restrict__ W2a, const float* __restrict__ W1b,
    const float* __restrict__ W2b, const float* __restrict__ emb,
    u16* __restrict__ Wpt, u16* __restrict__ W1at, u16* __restrict__ W2at,
    u16* __restrict__ W1bt, u16* __restrict__ W2bt, u16* __restrict__ embb,
    int* __restrict__ gcur, int NBK)
{
  int idx = blockIdx.x * 256 + threadIdx.x;
  if (idx < 512 * 128) {
    int k = idx >> 7, c = idx & 127;
    Wpt[(size_t)c * 512 + k] = f2b(Wp[idx]);
    return;
  }
  idx -= 512 * 128;
  if (idx < 4 * 128 * 128) {
    int w = idx >> 14, r = idx & (128 * 128 - 1);
    int k = r >> 7, c = r & 127;
    const float* s = (w == 0) ? W1a : (w == 1) ? W2a : (w == 2) ? W1b : W2b;
    u16* d = (w == 0) ? W1at : (w == 1) ? W2at : (w == 2) ? W1bt : W2bt;
    d[(size_t)c * 128 + k] = f2b(s[r]);
    return;
  }
  idx -= 4 * 128 * 128;
  if (idx < 100 * 128) { embb[idx] = f2b(emb[idx]); return; }
  idx -= 100 * 128;
  if (idx < NBK) gcur[idx] = 0;   // re-zeroed every call (graph replay safe)
}

// ---------------- fused: proj (blocks < gProj) | p1 edge binning (rest) ------
// proj: xb = bf16(pept @ Wpt^T + bp). ZERO LDS, ZERO barriers: both A and B
// fragments load direct from global (A: 16 rows x 128B coalesced; B: L2-hot
// Wpt, 200MB total L2 reads ~ 6us chip-wide). Round-16 lesson: proj was
// ~135us in EVERY LDS-staged variant -- the 2-barrier-per-K-step coupling
// was the invariant limiter, not the A-path. Waves now fully independent.
__global__ __launch_bounds__(256) void k_projp1(
    const float* __restrict__ A, const u16* __restrict__ Wt,
    const float* __restrict__ bias, u16* __restrict__ xb,
    const int* __restrict__ src, const int* __restrict__ dst,
    const int* __restrict__ attr, int* __restrict__ gcur,
    int* __restrict__ bspace, int nE, int NBK, int gProj, int N)
{
  __shared__ int lc[1024];   // used only by p1 branch (4KB, no occupancy impact)
  const int t = threadIdx.x;

  if ((int)blockIdx.x < gProj) {
    const int row0 = blockIdx.x * 64;
    const int lane = t & 63;
    const int wave = t >> 6;
    const int wm = wave >> 1, wn = wave & 1;   // 2x2 waves: 32 rows x 64 cols
    const int colg = lane & 15, rowg = lane >> 4;

    // per-lane A rows (clamped; OOB rows only feed OOB C rows, never stored)
    int arow0 = row0 + wm * 32 + colg;       if (arow0 >= N) arow0 = N - 1;
    int arow1 = row0 + wm * 32 + 16 + colg;  if (arow1 >= N) arow1 = N - 1;
    const float* aptr0 = A + (size_t)arow0 * 512 + rowg * 8;
    const float* aptr1 = A + (size_t)arow1 * 512 + rowg * 8;
    // per-lane B base: Wt[c][*], c = wn*64 + colg (+ni*16 per fragment)
    const u16* bptr = Wt + (size_t)(wn * 64 + colg) * 512 + rowg * 8;

    f32x4 acc[2][4];
#pragma unroll
    for (int ni = 0; ni < 4; ++ni) {
      float bc = bias[wn * 64 + ni * 16 + colg];
#pragma unroll
      for (int mi = 0; mi < 2; ++mi) acc[mi][ni] = (f32x4){bc, bc, bc, bc};
    }

#pragma unroll 4
    for (int k0 = 0; k0 < 512; k0 += 32) {
      short8v a[2], b[4];
      {
        float4 v0 = *reinterpret_cast<const float4*>(aptr0 + k0);
        float4 v1 = *reinterpret_cast<const float4*>(aptr0 + k0 + 4);
        union { short8v s; u16 us[8]; } pk;
        pk.us[0] = f2b(v0.x); pk.us[1] = f2b(v0.y);
        pk.us[2] = f2b(v0.z); pk.us[3] = f2b(v0.w);
        pk.us[4] = f2b(v1.x); pk.us[5] = f2b(v1.y);
        pk.us[6] = f2b(v1.z); pk.us[7] = f2b(v1.w);
        a[0] = pk.s;
      }
      {
        float4 v0 = *reinterpret_cast<const float4*>(aptr1 + k0);
        float4 v1 = *reinterpret_cast<const float4*>(aptr1 + k0 + 4);
        union { short8v s; u16 us[8]; } pk;
        pk.us[0] = f2b(v0.x); pk.us[1] = f2b(v0.y);
        pk.us[2] = f2b(v0.z); pk.us[3] = f2b(v0.w);
        pk.us[4] = f2b(v1.x); pk.us[5] = f2b(v1.y);
        pk.us[6] = f2b(v1.z); pk.us[7] = f2b(v1.w);
        a[1] = pk.s;
      }
#pragma unroll
      for (int ni = 0; ni < 4; ++ni)
        b[ni] = *reinterpret_cast<const short8v*>(bptr + (size_t)(ni * 16) * 512 + k0);
#pragma unroll
      for (int mi = 0; mi < 2; ++mi)
#pragma unroll
        for (int ni = 0; ni < 4; ++ni)
          acc[mi][ni] = __builtin_amdgcn_mfma_f32_16x16x32_bf16(a[mi], b[ni], acc[mi][ni], 0, 0, 0);
    }

#pragma unroll
    for (int mi = 0; mi < 2; ++mi) {
#pragma unroll
      for (int j = 0; j < 4; ++j) {
        int row = row0 + wm * 32 + mi * 16 + rowg * 4 + j;
        if (row >= N) continue;
#pragma unroll
        for (int ni = 0; ni < 4; ++ni) {
          int col = wn * 64 + ni * 16 + colg;
          xb[(size_t)row * 128 + col] = f2b(acc[mi][ni][j]);
        }
      }
    }
  } else {
    // ---- p1: bin edges into 128-node dst-buckets ----
    const int bb = blockIdx.x - gProj;
    const int e0 = bb * P1_CHUNK;
    const int e1 = min(e0 + P1_CHUNK, nE);
    for (int i = t; i < NBK; i += 256) lc[i] = 0;
    __syncthreads();
    for (int e = e0 + t; e < e1; e += 256) atomicAdd(&lc[dst[e] >> 7], 1);
    __syncthreads();
    for (int i = t; i < NBK; i += 256) {
      int c = lc[i];
      if (c) lc[i] = atomicAdd(&gcur[i], c);   // bucket-local base
    }
    __syncthreads();
    for (int e = e0 + t; e < e1; e += 256) {
      int d = dst[e];
      int b = d >> 7;
      int pos = atomicAdd(&lc[b], 1);
      if (pos < BKCAP)
        bspace[(size_t)b * BKCAP + pos] = src[e] | (attr[e] << 17) | ((d & 127) << 24);
    }
  }
}

// single-block scan of bucket counts (gcur) -> boff[NBK+1], off[N] = E
__global__ __launch_bounds__(1024) void k_bscan(
    const int* __restrict__ bcnt, int* __restrict__ boff,
    int* __restrict__ off, int NBK, int N)
{
  __shared__ int ps[1024];
  const int t = threadIdx.x;
  int v0 = (t < NBK) ? bcnt[t] : 0;
  ps[t] = v0;
  __syncthreads();
  for (int d = 1; d < 1024; d <<= 1) {
    int u = (t >= d) ? ps[t - d] : 0;
    __syncthreads();
    ps[t] += u;
    __syncthreads();
  }
  if (t < NBK) boff[t] = ps[t] - v0;
  if (t == 1023) {
    boff[NBK] = ps[1023];
    off[N] = ps[1023];
  }
}

// phase 2: one block per bucket. Derives per-node offsets (local count +
// 128-wide scan), writes off[] AND the compacted, exactly-ordered ep[].
__global__ __launch_bounds__(256) void k_p2(
    const int* __restrict__ bspace, const int* __restrict__ boff,
    const int* __restrict__ bcnt, int* __restrict__ ep,
    int* __restrict__ off, int N)
{
  __shared__ int cnt128[128];
  __shared__ int lc[128];
  __shared__ int wtot;
  const int b = blockIdx.x, t = threadIdx.x;
  const int nb = b * 128;
  const int nn = min(128, N - nb);
  const size_t inbase = (size_t)b * BKCAP;
  const int obase = boff[b];
  const int ecnt = bcnt[b];
  if (t < 128) cnt128[t] = 0;
  __syncthreads();
  for (int i = t; i < ecnt; i += 256)
    atomicAdd(&cnt128[(bspace[inbase + i] >> 24) & 127], 1);
  __syncthreads();
  if (t < 128) {
    const int lane = t & 63;
    int v = cnt128[t];
    int s = v;
    for (int d = 1; d < 64; d <<= 1) { int u = __shfl_up(s, d); if (lane >= d) s += u; }
    if (t == 63) wtot = s;          // wave-0 total
    __syncthreads();
    int excl = s - v + ((t >= 64) ? wtot : 0);
    int start = obase + excl;
    lc[t] = start;
    if (t < nn) off[nb + t] = start;
  } else {
    __syncthreads();
  }
  __syncthreads();
  for (int i = t; i < ecnt; i += 256) {
    int p = bspace[inbase + i];
    int pos = atomicAdd(&lc[(p >> 24) & 127], 1);
    ep[pos] = p & 0xFFFFFF;
  }
}

// am[i] = bf16( xb[i] + sum_{e in-edges(i)} relu(xb[src]+embb[attr]) )
// one wave/node; unroll-8 gather (16 loads in flight), split accumulators
__global__ __launch_bounds__(256) void k_aggA(
    const u16* __restrict__ xb, const int* __restrict__ ep,
    const int* __restrict__ off, const u16* __restrict__ embb,
    u16* __restrict__ am, int N)
{
  const int node = blockIdx.x * 4 + (threadIdx.x >> 6);
  if (node >= N) return;
  const int lane = threadIdx.x & 63;
  const int beg = off[node], end = off[node + 1];
  float ax0 = 0.f, ay0 = 0.f, ax1 = 0.f, ay1 = 0.f;
  int e = beg;
  for (; e + 8 <= end; e += 8) {
    int pp[8];
#pragma unroll
    for (int j = 0; j < 8; ++j) pp[j] = ep[e + j];
    unsigned xu[8], eu[8];
#pragma unroll
    for (int j = 0; j < 8; ++j) {
      xu[j] = *reinterpret_cast<const unsigned*>(xb + ((size_t)(pp[j] & 0x1FFFF) << 7) + lane * 2);
      eu[j] = *reinterpret_cast<const unsigned*>(embb + ((size_t)(pp[j] >> 17) << 7) + lane * 2);
    }
#pragma unroll
    for (int j = 0; j < 8; j += 2) {
      ax0 += fmaxf(blo(xu[j]) + blo(eu[j]), 0.f);
      ay0 += fmaxf(bhi(xu[j]) + bhi(eu[j]), 0.f);
      ax1 += fmaxf(blo(xu[j + 1]) + blo(eu[j + 1]), 0.f);
      ay1 += fmaxf(bhi(xu[j + 1]) + bhi(eu[j + 1]), 0.f);
    }
  }
  for (; e < end; ++e) {
    int p = ep[e];
    unsigned xu = *reinterpret_cast<const unsigned*>(xb + ((size_t)(p & 0x1FFFF) << 7) + lane * 2);
    unsigned eu = *reinterpret_cast<const unsigned*>(embb + ((size_t)(p >> 17) << 7) + lane * 2);
    ax0 += fmaxf(blo(xu) + blo(eu), 0.f);
    ay0 += fmaxf(bhi(xu) + bhi(eu), 0.f);
  }
  unsigned xo = *reinterpret_cast<const unsigned*>(xb + ((size_t)node << 7) + lane * 2);
  float ax = ax0 + ax1 + blo(xo);
  float ay = ay0 + ay1 + bhi(xo);
  unsigned w = ((unsigned)f2b(ay) << 16) | (unsigned)f2b(ax);
  *reinterpret_cast<unsigned*>(am + ((size_t)node << 7) + lane * 2) = w;
}

// ---------------- fused MLP: out = relu(am@W1+b1)@W2 + b2 + res ----------------
// EPI2: 2 = +res -> bf16 out (in-place xb safe), 3 = +res -> f32 out
template <int EPI2>
__global__ __launch_bounds__(256) void k_mlpf(
    const u16* __restrict__ am, const u16* __restrict__ W1t,
    const float* __restrict__ b1, const u16* __restrict__ W2t,
    const float* __restrict__ b2, const u16* __restrict__ resb,
    void* __restrict__ outp, int N)
{
  __shared__ u16 As[64 * 128];   // 16KB: am tile, then h (row stride 256B)
  __shared__ u16 Bs[128 * 128];  // 32KB: W1, then W2
  const int t = threadIdx.x;
  const int row0 = blockIdx.x * 64;
  const int lane = t & 63, wave = t >> 6;
  const int wm = wave >> 1, wn = wave & 1;   // 2x2 waves: 32 rows x 64 cols
  const int colg = lane & 15, rowg = lane >> 4;

#pragma unroll
  for (int i = 0; i < 4; ++i) {
    int idx = t + i * 256, r = idx >> 4, k8 = idx & 15;
    int4 v = make_int4(0, 0, 0, 0);
    if (row0 + r < N)
      v = *reinterpret_cast<const int4*>(am + (size_t)(row0 + r) * 128 + k8 * 8);
    int byteoff = (r * 256 + k8 * 16) ^ ((r & 7) << 4);
    *reinterpret_cast<int4*>((char*)As + byteoff) = v;
  }
#pragma unroll
  for (int i = 0; i < 8; ++i) {
    int idx = t + i * 256, c = idx >> 4, k8 = idx & 15;
    int4 v = *reinterpret_cast<const int4*>(W1t + (size_t)c * 128 + k8 * 8);
    int byteoff = (c * 256 + k8 * 16) ^ ((c & 7) << 4);
    *reinterpret_cast<int4*>((char*)Bs + byteoff) = v;
  }
  __syncthreads();

  f32x4 acc[2][4];
#pragma unroll
  for (int ni = 0; ni < 4; ++ni) {
    float bc = b1[wn * 64 + ni * 16 + colg];
#pragma unroll
    for (int mi = 0; mi < 2; ++mi) acc[mi][ni] = (f32x4){bc, bc, bc, bc};
  }
#pragma unroll
  for (int kk = 0; kk < 128; kk += 32) {
    short8v a[2], b[4];
#pragma unroll
    for (int mi = 0; mi < 2; ++mi) {
      int r = wm * 32 + mi * 16 + colg;
      int byteoff = (r * 256 + (kk + rowg * 8) * 2) ^ ((r & 7) << 4);
      a[mi] = *reinterpret_cast<const short8v*>((const char*)As + byteoff);
    }
#pragma unroll
    for (int ni = 0; ni < 4; ++ni) {
      int c = wn * 64 + ni * 16 + colg;
      int byteoff = (c * 256 + (kk + rowg * 8) * 2) ^ ((c & 7) << 4);
      b[ni] = *reinterpret_cast<const short8v*>((const char*)Bs + byteoff);
    }
#pragma unroll
    for (int mi = 0; mi < 2; ++mi)
#pragma unroll
      for (int ni = 0; ni < 4; ++ni)
        acc[mi][ni] = __builtin_amdgcn_mfma_f32_16x16x32_bf16(a[mi], b[ni], acc[mi][ni], 0, 0, 0);
  }
  __syncthreads();   // all As/Bs reads complete before overwrite

  // h = relu(acc) -> As (bf16), stage W2 -> Bs
#pragma unroll
  for (int mi = 0; mi < 2; ++mi) {
#pragma unroll
    for (int j = 0; j < 4; ++j) {
      int row = wm * 32 + mi * 16 + rowg * 4 + j;
#pragma unroll
      for (int ni = 0; ni < 4; ++ni) {
        int col = wn * 64 + ni * 16 + colg;
        int byteoff = (row * 256 + col * 2) ^ ((row & 7) << 4);
        *reinterpret_cast<u16*>((char*)As + byteoff) = f2b(fmaxf(acc[mi][ni][j], 0.f));
      }
    }
  }
#pragma unroll
  for (int i = 0; i < 8; ++i) {
    int idx = t + i * 256, c = idx >> 4, k8 = idx & 15;
    int4 v = *reinterpret_cast<const int4*>(W2t + (size_t)c * 128 + k8 * 8);
    int byteoff = (c * 256 + k8 * 16) ^ ((c & 7) << 4);
    *reinterpret_cast<int4*>((char*)Bs + byteoff) = v;
  }
  __syncthreads();

#pragma unroll
  for (int ni = 0; ni < 4; ++ni) {
    float bc = b2[wn * 64 + ni * 16 + colg];
#pragma unroll
    for (int mi = 0; mi < 2; ++mi) acc[mi][ni] = (f32x4){bc, bc, bc, bc};
  }
#pragma unroll
  for (int kk = 0; kk < 128; kk += 32) {
    short8v a[2], b[4];
#pragma unroll
    for (int mi = 0; mi < 2; ++mi) {
      int r = wm * 32 + mi * 16 + colg;
      int byteoff = (r * 256 + (kk + rowg * 8) * 2) ^ ((r & 7) << 4);
      a[mi] = *reinterpret_cast<const short8v*>((const char*)As + byteoff);
    }
#pragma unroll
    for (int ni = 0; ni < 4; ++ni) {
      int c = wn * 64 + ni * 16 + colg;
      int byteoff = (c * 256 + (kk + rowg * 8) * 2) ^ ((c & 7) << 4);
      b[ni] = *reinterpret_cast<const short8v*>((const char*)Bs + byteoff);
    }
#pragma unroll
    for (int mi = 0; mi < 2; ++mi)
#pragma unroll
      for (int ni = 0; ni < 4; ++ni)
        acc[mi][ni] = __builtin_amdgcn_mfma_f32_16x16x32_bf16(a[mi], b[ni], acc[mi][ni], 0, 0, 0);
  }

#pragma unroll
  for (int mi = 0; mi < 2; ++mi) {
#pragma unroll
    for (int j = 0; j < 4; ++j) {
      int row = row0 + wm * 32 + mi * 16 + rowg * 4 + j;
      if (row >= N) continue;
#pragma unroll
      for (int ni = 0; ni < 4; ++ni) {
        int col = wn * 64 + ni * 16 + colg;
        float v = acc[mi][ni][j] + bs2f(resb[(size_t)row * 128 + col]);
        if (EPI2 == 2) ((u16*)outp)[(size_t)row * 128 + col] = f2b(v);
        else           ((float*)outp)[(size_t)row * 128 + col] = v;
      }
    }
  }
}

// ---------------- launcher ----------------
extern "C" void kernel_launch(void* const* d_in, const int* in_sizes, int n_in,
                              void* d_out, int out_size, void* d_ws, size_t ws_size,
                              hipStream_t stream)
{
  const float* pept  = (const float*)d_in[0];
  const int*   eidx  = (const int*)d_in[1];
  const int*   eattr = (const int*)d_in[2];
  const float* Wp  = (const float*)d_in[3];
  const float* bp  = (const float*)d_in[4];
  const float* emb = (const float*)d_in[5];
  // d_in[6]=cls_token, d_in[7]=cls_edge: dead for the output (CLS node is never
  // a source and row N is dropped) -> skipped.
  const float* W1a = (const float*)d_in[8];
  const float* b1a = (const float*)d_in[9];
  const float* W2a = (const float*)d_in[10];
  const float* b2a = (const float*)d_in[11];
  const float* W1b = (const float*)d_in[12];
  const float* b1b = (const float*)d_in[13];
  const float* W2b = (const float*)d_in[14];
  const float* b2b = (const float*)d_in[15];

  const int N = in_sizes[0] / 512;
  const int E = in_sizes[1] / 2;
  const int* srcp = eidx;
  const int* dstp = eidx + E;
  const int NBK = (N + 127) / 128;       // dst buckets

  char* ws = (char*)d_ws;
  char* p = ws;
  u16* xb  = (u16*)p;               p += (size_t)N * 128 * 2;   // bf16 x master
  u16* am  = (u16*)p;               p += (size_t)N * 128 * 2;   // bf16 A for MLP
  int* off    = (int*)p;            p += (size_t)(N + 1) * 4;
  int* boff   = (int*)p;            p += (size_t)(NBK + 1) * 4;
  int* gcur   = (int*)p;            p += (size_t)NBK * 4;
  int* ep     = (int*)p;            p += (size_t)E * 4;
  int* bspace = (int*)p;            p += (size_t)NBK * BKCAP * 4;
  u16* Wpt  = (u16*)p;              p += (size_t)512 * 128 * 2;
  u16* W1at = (u16*)p;              p += (size_t)128 * 128 * 2;
  u16* W2at = (u16*)p;              p += (size_t)128 * 128 * 2;
  u16* W1bt = (u16*)p;              p += (size_t)128 * 128 * 2;
  u16* W2bt = (u16*)p;              p += (size_t)128 * 128 * 2;
  u16* embb = (u16*)p;              p += (size_t)100 * 128 * 2;

  const int gGemm = (N + 63) / 64;
  const int gAgg  = (N + 3) / 4;
  const int gP1   = (E + P1_CHUNK - 1) / P1_CHUNK;
  const int gPrep = (512 * 128 + 4 * 128 * 128 + 100 * 128 + 1024 + 255) / 256;

  // prep: all weight transposes via coalesced global writes + gcur zeroing
  hipLaunchKernelGGL(k_prepw_all, dim3(gPrep), dim3(256), 0, stream,
                     Wp, W1a, W2a, W1b, W2b, emb,
                     Wpt, W1at, W2at, W1bt, W2bt, embb, gcur, NBK);

  // proj (barrier-free direct-load MFMA) overlapped with p1 edge binning
  hipLaunchKernelGGL(k_projp1, dim3(gGemm + gP1), dim3(256), 0, stream,
                     pept, Wpt, bp, xb, srcp, dstp, eattr, gcur, bspace,
                     E, NBK, gGemm, N);

  // bucket scan, then compact into exact CSR order
  hipLaunchKernelGGL(k_bscan, dim3(1), dim3(1024), 0, stream, gcur, boff, off, NBK, N);
  hipLaunchKernelGGL(k_p2, dim3(NBK), dim3(256), 0, stream, bspace, boff, gcur, ep, off, N);

  // ---- layer a: am = agg(xb); xb = mlp(am) + xb  (fused, in-place) ----
  hipLaunchKernelGGL(k_aggA, dim3(gAgg), dim3(256), 0, stream, xb, ep, off, embb, am, N);
  hipLaunchKernelGGL((k_mlpf<2>), dim3(gGemm), dim3(256), 0, stream,
                     am, W1at, b1a, W2at, b2a, xb, xb, N);

  // ---- layer b: am = agg(xb); d_out = mlp(am) + xb  (f32 out) ----
  hipLaunchKernelGGL(k_aggA, dim3(gAgg), dim3(256), 0, stream, xb, ep, off, embb, am, N);
  hipLaunchKernelGGL((k_mlpf<3>), dim3(gGemm), dim3(256), 0, stream,
                     am, W1bt, b1b, W2bt, b2b, xb, d_out, N);
}

// Round 18
// 371.639 us; speedup vs baseline: 1.0114x; 1.0114x over previous
//
#include <hip/hip_runtime.h>

typedef unsigned short u16;
typedef __attribute__((ext_vector_type(8))) short short8v;
typedef __attribute__((ext_vector_type(4))) float f32x4;

#define P1_CHUNK 8192
#define BKCAP    4096   // fixed bucket capacity: mean fill 2046, ~45-sigma margin

__device__ __forceinline__ u16 f2b(float f) {
  union { float fv; unsigned int i; } v; v.fv = f;
  unsigned int x = v.i;
  return (u16)((x + 0x7FFFu + ((x >> 16) & 1u)) >> 16);
}
__device__ __forceinline__ float bs2f(u16 u) {
  union { unsigned i; float f; } v; v.i = (unsigned)u << 16; return v.f;
}
__device__ __forceinline__ float blo(unsigned u) {
  union { unsigned i; float f; } v; v.i = u << 16; return v.f;
}
__device__ __forceinline__ float bhi(unsigned u) {
  union { unsigned i; float f; } v; v.i = u & 0xFFFF0000u; return v.f;
}

// ---------------- prep: weight transposes + emb + gcur zero + pept->bf16 ----
// (coalesced global writes only -- round-14 lesson). pept conversion halves
// proj's A-stream bytes (204.8MB fp32 -> 102.4MB bf16): round-17 hypothesis
// is proj was BYTES-bound, the only untouched variable across 4 variants.
__global__ __launch_bounds__(256) void k_prepw_all(
    const float* __restrict__ Wp, const float* __restrict__ W1a,
    const float* __restrict__ W2a, const float* __restrict__ W1b,
    const float* __restrict__ W2b, const float* __restrict__ emb,
    const float* __restrict__ pept,
    u16* __restrict__ Wpt, u16* __restrict__ W1at, u16* __restrict__ W2at,
    u16* __restrict__ W1bt, u16* __restrict__ W2bt, u16* __restrict__ embb,
    int* __restrict__ gcur, u16* __restrict__ xpb, int NBK, int N)
{
  int idx = blockIdx.x * 256 + threadIdx.x;
  if (idx < 512 * 128) {
    int k = idx >> 7, c = idx & 127;
    Wpt[(size_t)c * 512 + k] = f2b(Wp[idx]);
    return;
  }
  idx -= 512 * 128;
  if (idx < 4 * 128 * 128) {
    int w = idx >> 14, r = idx & (128 * 128 - 1);
    int k = r >> 7, c = r & 127;
    const float* s = (w == 0) ? W1a : (w == 1) ? W2a : (w == 2) ? W1b : W2b;
    u16* d = (w == 0) ? W1at : (w == 1) ? W2at : (w == 2) ? W1bt : W2bt;
    d[(size_t)c * 128 + k] = f2b(s[r]);
    return;
  }
  idx -= 4 * 128 * 128;
  if (idx < 100 * 128) { embb[idx] = f2b(emb[idx]); return; }
  idx -= 100 * 128;
  if (idx < 1024) { if (idx < NBK) gcur[idx] = 0; return; }
  idx -= 1024;
  // pept -> bf16: 8 floats per thread (2x float4 read, 1x int4 write)
  if (idx < N * 64) {
    const float* s = pept + (size_t)idx * 8;
    float4 v0 = *reinterpret_cast<const float4*>(s);
    float4 v1 = *reinterpret_cast<const float4*>(s + 4);
    union { int4 i4; u16 us[8]; } pk;
    pk.us[0] = f2b(v0.x); pk.us[1] = f2b(v0.y);
    pk.us[2] = f2b(v0.z); pk.us[3] = f2b(v0.w);
    pk.us[4] = f2b(v1.x); pk.us[5] = f2b(v1.y);
    pk.us[6] = f2b(v1.z); pk.us[7] = f2b(v1.w);
    *reinterpret_cast<int4*>(xpb + (size_t)idx * 8) = pk.i4;
  }
}

// ---------------- fused: proj (blocks < gProj) | p1 edge binning (rest) ------
// proj: xb = bf16(xpb @ Wpt^T + bp), bf16 A staging (round-13 int4 path,
// conflict-free). Same structure as round-15 best, half the A bytes.
__global__ __launch_bounds__(256) void k_projp1(
    const u16* __restrict__ Ab, const u16* __restrict__ Wt,
    const float* __restrict__ bias, u16* __restrict__ xb,
    const int* __restrict__ src, const int* __restrict__ dst,
    const int* __restrict__ attr, int* __restrict__ gcur,
    int* __restrict__ bspace, int nE, int NBK, int gProj, int N)
{
  __shared__ __align__(16) char smem[24576];   // proj: As 8KB + Bs 16KB; p1: lc 4KB
  const int t = threadIdx.x;

  if ((int)blockIdx.x < gProj) {
    u16* As = (u16*)smem;            // [64][64], row stride 128B, ^((r&7)<<4)
    u16* Bs = (u16*)(smem + 8192);   // [128][64], same swizzle
    const int row0 = blockIdx.x * 64;
    const int lane = t & 63;
    const int wave = t >> 6;
    const int wm = wave >> 1, wn = wave & 1;   // 2x2 waves: 32 rows x 64 cols
    const int colg = lane & 15, rowg = lane >> 4;

    f32x4 acc[2][4];
#pragma unroll
    for (int ni = 0; ni < 4; ++ni) {
      float bc = bias[wn * 64 + ni * 16 + colg];
#pragma unroll
      for (int mi = 0; mi < 2; ++mi) acc[mi][ni] = (f32x4){bc, bc, bc, bc};
    }

    for (int k0 = 0; k0 < 512; k0 += 64) {
      // stage A tile (bf16, 512 int4 = 64 rows x 8)
#pragma unroll
      for (int i = 0; i < 2; ++i) {
        int idx = t + i * 256;
        int r = idx >> 3, k8 = idx & 7;
        int4 v = make_int4(0, 0, 0, 0);
        if (row0 + r < N)
          v = *reinterpret_cast<const int4*>(Ab + (size_t)(row0 + r) * 512 + k0 + k8 * 8);
        int byteoff = (r * 128 + k8 * 16) ^ ((r & 7) << 4);
        *reinterpret_cast<int4*>((char*)As + byteoff) = v;
      }
      // stage B tile (bf16 Wpt, 1024 int4 = 128 cols x 8)
#pragma unroll
      for (int i = 0; i < 4; ++i) {
        int idx = t + i * 256;
        int c = idx >> 3, k8 = idx & 7;
        int4 v = *reinterpret_cast<const int4*>(Wt + (size_t)c * 512 + k0 + k8 * 8);
        int byteoff = (c * 128 + k8 * 16) ^ ((c & 7) << 4);
        *reinterpret_cast<int4*>((char*)Bs + byteoff) = v;
      }
      __syncthreads();
#pragma unroll
      for (int kk = 0; kk < 64; kk += 32) {
        short8v a[2], b[4];
#pragma unroll
        for (int mi = 0; mi < 2; ++mi) {
          int r = wm * 32 + mi * 16 + colg;
          int byteoff = (r * 128 + (kk + rowg * 8) * 2) ^ ((r & 7) << 4);
          a[mi] = *reinterpret_cast<const short8v*>((const char*)As + byteoff);
        }
#pragma unroll
        for (int ni = 0; ni < 4; ++ni) {
          int c = wn * 64 + ni * 16 + colg;
          int byteoff = (c * 128 + (kk + rowg * 8) * 2) ^ ((c & 7) << 4);
          b[ni] = *reinterpret_cast<const short8v*>((const char*)Bs + byteoff);
        }
#pragma unroll
        for (int mi = 0; mi < 2; ++mi)
#pragma unroll
          for (int ni = 0; ni < 4; ++ni)
            acc[mi][ni] = __builtin_amdgcn_mfma_f32_16x16x32_bf16(a[mi], b[ni], acc[mi][ni], 0, 0, 0);
      }
      __syncthreads();
    }

#pragma unroll
    for (int mi = 0; mi < 2; ++mi) {
#pragma unroll
      for (int j = 0; j < 4; ++j) {
        int row = row0 + wm * 32 + mi * 16 + rowg * 4 + j;
        if (row >= N) continue;
#pragma unroll
        for (int ni = 0; ni < 4; ++ni) {
          int col = wn * 64 + ni * 16 + colg;
          xb[(size_t)row * 128 + col] = f2b(acc[mi][ni][j]);
        }
      }
    }
  } else {
    // ---- p1: bin edges into 128-node dst-buckets ----
    int* lc = (int*)smem;             // NBK <= 1024
    const int bb = blockIdx.x - gProj;
    const int e0 = bb * P1_CHUNK;
    const int e1 = min(e0 + P1_CHUNK, nE);
    for (int i = t; i < NBK; i += 256) lc[i] = 0;
    __syncthreads();
    for (int e = e0 + t; e < e1; e += 256) atomicAdd(&lc[dst[e] >> 7], 1);
    __syncthreads();
    for (int i = t; i < NBK; i += 256) {
      int c = lc[i];
      if (c) lc[i] = atomicAdd(&gcur[i], c);   // bucket-local base
    }
    __syncthreads();
    for (int e = e0 + t; e < e1; e += 256) {
      int d = dst[e];
      int b = d >> 7;
      int pos = atomicAdd(&lc[b], 1);
      if (pos < BKCAP)
        bspace[(size_t)b * BKCAP + pos] = src[e] | (attr[e] << 17) | ((d & 127) << 24);
    }
  }
}

// single-block scan of bucket counts (gcur) -> boff[NBK+1], off[N] = E
__global__ __launch_bounds__(1024) void k_bscan(
    const int* __restrict__ bcnt, int* __restrict__ boff,
    int* __restrict__ off, int NBK, int N)
{
  __shared__ int ps[1024];
  const int t = threadIdx.x;
  int v0 = (t < NBK) ? bcnt[t] : 0;
  ps[t] = v0;
  __syncthreads();
  for (int d = 1; d < 1024; d <<= 1) {
    int u = (t >= d) ? ps[t - d] : 0;
    __syncthreads();
    ps[t] += u;
    __syncthreads();
  }
  if (t < NBK) boff[t] = ps[t] - v0;
  if (t == 1023) {
    boff[NBK] = ps[1023];
    off[N] = ps[1023];
  }
}

// phase 2: one block per bucket. Derives per-node offsets (local count +
// 128-wide scan), writes off[] AND the compacted, exactly-ordered ep[].
__global__ __launch_bounds__(256) void k_p2(
    const int* __restrict__ bspace, const int* __restrict__ boff,
    const int* __restrict__ bcnt, int* __restrict__ ep,
    int* __restrict__ off, int N)
{
  __shared__ int cnt128[128];
  __shared__ int lc[128];
  __shared__ int wtot;
  const int b = blockIdx.x, t = threadIdx.x;
  const int nb = b * 128;
  const int nn = min(128, N - nb);
  const size_t inbase = (size_t)b * BKCAP;
  const int obase = boff[b];
  const int ecnt = bcnt[b];
  if (t < 128) cnt128[t] = 0;
  __syncthreads();
  for (int i = t; i < ecnt; i += 256)
    atomicAdd(&cnt128[(bspace[inbase + i] >> 24) & 127], 1);
  __syncthreads();
  if (t < 128) {
    const int lane = t & 63;
    int v = cnt128[t];
    int s = v;
    for (int d = 1; d < 64; d <<= 1) { int u = __shfl_up(s, d); if (lane >= d) s += u; }
    if (t == 63) wtot = s;          // wave-0 total
    __syncthreads();
    int excl = s - v + ((t >= 64) ? wtot : 0);
    int start = obase + excl;
    lc[t] = start;
    if (t < nn) off[nb + t] = start;
  } else {
    __syncthreads();
  }
  __syncthreads();
  for (int i = t; i < ecnt; i += 256) {
    int p = bspace[inbase + i];
    int pos = atomicAdd(&lc[(p >> 24) & 127], 1);
    ep[pos] = p & 0xFFFFFF;
  }
}

// am[i] = bf16( xb[i] + sum_{e in-edges(i)} relu(xb[src]+embb[attr]) )
// one wave/node; unroll-8 gather (16 loads in flight), split accumulators
__global__ __launch_bounds__(256) void k_aggA(
    const u16* __restrict__ xb, const int* __restrict__ ep,
    const int* __restrict__ off, const u16* __restrict__ embb,
    u16* __restrict__ am, int N)
{
  const int node = blockIdx.x * 4 + (threadIdx.x >> 6);
  if (node >= N) return;
  const int lane = threadIdx.x & 63;
  const int beg = off[node], end = off[node + 1];
  float ax0 = 0.f, ay0 = 0.f, ax1 = 0.f, ay1 = 0.f;
  int e = beg;
  for (; e + 8 <= end; e += 8) {
    int pp[8];
#pragma unroll
    for (int j = 0; j < 8; ++j) pp[j] = ep[e + j];
    unsigned xu[8], eu[8];
#pragma unroll
    for (int j = 0; j < 8; ++j) {
      xu[j] = *reinterpret_cast<const unsigned*>(xb + ((size_t)(pp[j] & 0x1FFFF) << 7) + lane * 2);
      eu[j] = *reinterpret_cast<const unsigned*>(embb + ((size_t)(pp[j] >> 17) << 7) + lane * 2);
    }
#pragma unroll
    for (int j = 0; j < 8; j += 2) {
      ax0 += fmaxf(blo(xu[j]) + blo(eu[j]), 0.f);
      ay0 += fmaxf(bhi(xu[j]) + bhi(eu[j]), 0.f);
      ax1 += fmaxf(blo(xu[j + 1]) + blo(eu[j + 1]), 0.f);
      ay1 += fmaxf(bhi(xu[j + 1]) + bhi(eu[j + 1]), 0.f);
    }
  }
  for (; e < end; ++e) {
    int p = ep[e];
    unsigned xu = *reinterpret_cast<const unsigned*>(xb + ((size_t)(p & 0x1FFFF) << 7) + lane * 2);
    unsigned eu = *reinterpret_cast<const unsigned*>(embb + ((size_t)(p >> 17) << 7) + lane * 2);
    ax0 += fmaxf(blo(xu) + blo(eu), 0.f);
    ay0 += fmaxf(bhi(xu) + bhi(eu), 0.f);
  }
  unsigned xo = *reinterpret_cast<const unsigned*>(xb + ((size_t)node << 7) + lane * 2);
  float ax = ax0 + ax1 + blo(xo);
  float ay = ay0 + ay1 + bhi(xo);
  unsigned w = ((unsigned)f2b(ay) << 16) | (unsigned)f2b(ax);
  *reinterpret_cast<unsigned*>(am + ((size_t)node << 7) + lane * 2) = w;
}

// ---------------- fused MLP: out = relu(am@W1+b1)@W2 + b2 + res ----------------
// EPI2: 2 = +res -> bf16 out (in-place xb safe), 3 = +res -> f32 out
template <int EPI2>
__global__ __launch_bounds__(256) void k_mlpf(
    const u16* __restrict__ am, const u16* __restrict__ W1t,
    const float* __restrict__ b1, const u16* __restrict__ W2t,
    const float* __restrict__ b2, const u16* __restrict__ resb,
    void* __restrict__ outp, int N)
{
  __shared__ u16 As[64 * 128];   // 16KB: am tile, then h (row stride 256B)
  __shared__ u16 Bs[128 * 128];  // 32KB: W1, then W2
  const int t = threadIdx.x;
  const int row0 = blockIdx.x * 64;
  const int lane = t & 63, wave = t >> 6;
  const int wm = wave >> 1, wn = wave & 1;   // 2x2 waves: 32 rows x 64 cols
  const int colg = lane & 15, rowg = lane >> 4;

#pragma unroll
  for (int i = 0; i < 4; ++i) {
    int idx = t + i * 256, r = idx >> 4, k8 = idx & 15;
    int4 v = make_int4(0, 0, 0, 0);
    if (row0 + r < N)
      v = *reinterpret_cast<const int4*>(am + (size_t)(row0 + r) * 128 + k8 * 8);
    int byteoff = (r * 256 + k8 * 16) ^ ((r & 7) << 4);
    *reinterpret_cast<int4*>((char*)As + byteoff) = v;
  }
#pragma unroll
  for (int i = 0; i < 8; ++i) {
    int idx = t + i * 256, c = idx >> 4, k8 = idx & 15;
    int4 v = *reinterpret_cast<const int4*>(W1t + (size_t)c * 128 + k8 * 8);
    int byteoff = (c * 256 + k8 * 16) ^ ((c & 7) << 4);
    *reinterpret_cast<int4*>((char*)Bs + byteoff) = v;
  }
  __syncthreads();

  f32x4 acc[2][4];
#pragma unroll
  for (int ni = 0; ni < 4; ++ni) {
    float bc = b1[wn * 64 + ni * 16 + colg];
#pragma unroll
    for (int mi = 0; mi < 2; ++mi) acc[mi][ni] = (f32x4){bc, bc, bc, bc};
  }
#pragma unroll
  for (int kk = 0; kk < 128; kk += 32) {
    short8v a[2], b[4];
#pragma unroll
    for (int mi = 0; mi < 2; ++mi) {
      int r = wm * 32 + mi * 16 + colg;
      int byteoff = (r * 256 + (kk + rowg * 8) * 2) ^ ((r & 7) << 4);
      a[mi] = *reinterpret_cast<const short8v*>((const char*)As + byteoff);
    }
#pragma unroll
    for (int ni = 0; ni < 4; ++ni) {
      int c = wn * 64 + ni * 16 + colg;
      int byteoff = (c * 256 + (kk + rowg * 8) * 2) ^ ((c & 7) << 4);
      b[ni] = *reinterpret_cast<const short8v*>((const char*)Bs + byteoff);
    }
#pragma unroll
    for (int mi = 0; mi < 2; ++mi)
#pragma unroll
      for (int ni = 0; ni < 4; ++ni)
        acc[mi][ni] = __builtin_amdgcn_mfma_f32_16x16x32_bf16(a[mi], b[ni], acc[mi][ni], 0, 0, 0);
  }
  __syncthreads();   // all As/Bs reads complete before overwrite

  // h = relu(acc) -> As (bf16), stage W2 -> Bs
#pragma unroll
  for (int mi = 0; mi < 2; ++mi) {
#pragma unroll
    for (int j = 0; j < 4; ++j) {
      int row = wm * 32 + mi * 16 + rowg * 4 + j;
#pragma unroll
      for (int ni = 0; ni < 4; ++ni) {
        int col = wn * 64 + ni * 16 + colg;
        int byteoff = (row * 256 + col * 2) ^ ((row & 7) << 4);
        *reinterpret_cast<u16*>((char*)As + byteoff) = f2b(fmaxf(acc[mi][ni][j], 0.f));
      }
    }
  }
#pragma unroll
  for (int i = 0; i < 8; ++i) {
    int idx = t + i * 256, c = idx >> 4, k8 = idx & 15;
    int4 v = *reinterpret_cast<const int4*>(W2t + (size_t)c * 128 + k8 * 8);
    int byteoff = (c * 256 + k8 * 16) ^ ((c & 7) << 4);
    *reinterpret_cast<int4*>((char*)Bs + byteoff) = v;
  }
  __syncthreads();

#pragma unroll
  for (int ni = 0; ni < 4; ++ni) {
    float bc = b2[wn * 64 + ni * 16 + colg];
#pragma unroll
    for (int mi = 0; mi < 2; ++mi) acc[mi][ni] = (f32x4){bc, bc, bc, bc};
  }
#pragma unroll
  for (int kk = 0; kk < 128; kk += 32) {
    short8v a[2], b[4];
#pragma unroll
    for (int mi = 0; mi < 2; ++mi) {
      int r = wm * 32 + mi * 16 + colg;
      int byteoff = (r * 256 + (kk + rowg * 8) * 2) ^ ((r & 7) << 4);
      a[mi] = *reinterpret_cast<const short8v*>((const char*)As + byteoff);
    }
#pragma unroll
    for (int ni = 0; ni < 4; ++ni) {
      int c = wn * 64 + ni * 16 + colg;
      int byteoff = (c * 256 + (kk + rowg * 8) * 2) ^ ((c & 7) << 4);
      b[ni] = *reinterpret_cast<const short8v*>((const char*)Bs + byteoff);
    }
#pragma unroll
    for (int mi = 0; mi < 2; ++mi)
#pragma unroll
      for (int ni = 0; ni < 4; ++ni)
        acc[mi][ni] = __builtin_amdgcn_mfma_f32_16x16x32_bf16(a[mi], b[ni], acc[mi][ni], 0, 0, 0);
  }

#pragma unroll
  for (int mi = 0; mi < 2; ++mi) {
#pragma unroll
    for (int j = 0; j < 4; ++j) {
      int row = row0 + wm * 32 + mi * 16 + rowg * 4 + j;
      if (row >= N) continue;
#pragma unroll
      for (int ni = 0; ni < 4; ++ni) {
        int col = wn * 64 + ni * 16 + colg;
        float v = acc[mi][ni][j] + bs2f(resb[(size_t)row * 128 + col]);
        if (EPI2 == 2) ((u16*)outp)[(size_t)row * 128 + col] = f2b(v);
        else           ((float*)outp)[(size_t)row * 128 + col] = v;
      }
    }
  }
}

// ---------------- launcher ----------------
extern "C" void kernel_launch(void* const* d_in, const int* in_sizes, int n_in,
                              void* d_out, int out_size, void* d_ws, size_t ws_size,
                              hipStream_t stream)
{
  const float* pept  = (const float*)d_in[0];
  const int*   eidx  = (const int*)d_in[1];
  const int*   eattr = (const int*)d_in[2];
  const float* Wp  = (const float*)d_in[3];
  const float* bp  = (const float*)d_in[4];
  const float* emb = (const float*)d_in[5];
  // d_in[6]=cls_token, d_in[7]=cls_edge: dead for the output (CLS node is never
  // a source and row N is dropped) -> skipped.
  const float* W1a = (const float*)d_in[8];
  const float* b1a = (const float*)d_in[9];
  const float* W2a = (const float*)d_in[10];
  const float* b2a = (const float*)d_in[11];
  const float* W1b = (const float*)d_in[12];
  const float* b1b = (const float*)d_in[13];
  const float* W2b = (const float*)d_in[14];
  const float* b2b = (const float*)d_in[15];

  const int N = in_sizes[0] / 512;
  const int E = in_sizes[1] / 2;
  const int* srcp = eidx;
  const int* dstp = eidx + E;
  const int NBK = (N + 127) / 128;       // dst buckets

  char* ws = (char*)d_ws;
  char* p = ws;
  u16* xb  = (u16*)p;               p += (size_t)N * 128 * 2;   // bf16 x master
  u16* am  = (u16*)p;               p += (size_t)N * 128 * 2;   // bf16 A for MLP
  u16* xpb = (u16*)p;               p += (size_t)N * 512 * 2;   // bf16 pept
  int* off    = (int*)p;            p += (size_t)(N + 1) * 4;
  int* boff   = (int*)p;            p += (size_t)(NBK + 1) * 4;
  int* gcur   = (int*)p;            p += (size_t)NBK * 4;
  int* ep     = (int*)p;            p += (size_t)E * 4;
  int* bspace = (int*)p;            p += (size_t)NBK * BKCAP * 4;
  u16* Wpt  = (u16*)p;              p += (size_t)512 * 128 * 2;
  u16* W1at = (u16*)p;              p += (size_t)128 * 128 * 2;
  u16* W2at = (u16*)p;              p += (size_t)128 * 128 * 2;
  u16* W1bt = (u16*)p;              p += (size_t)128 * 128 * 2;
  u16* W2bt = (u16*)p;              p += (size_t)128 * 128 * 2;
  u16* embb = (u16*)p;              p += (size_t)100 * 128 * 2;

  const int gGemm = (N + 63) / 64;
  const int gAgg  = (N + 3) / 4;
  const int gP1   = (E + P1_CHUNK - 1) / P1_CHUNK;
  const int gPrep = (512 * 128 + 4 * 128 * 128 + 100 * 128 + 1024 + N * 64 + 255) / 256;

  // prep: weight transposes + gcur zero + pept->bf16 (all coalesced streams)
  hipLaunchKernelGGL(k_prepw_all, dim3(gPrep), dim3(256), 0, stream,
                     Wp, W1a, W2a, W1b, W2b, emb, pept,
                     Wpt, W1at, W2at, W1bt, W2bt, embb, gcur, xpb, NBK, N);

  // proj (bf16 A, round-15 staging structure) overlapped with p1 edge binning
  hipLaunchKernelGGL(k_projp1, dim3(gGemm + gP1), dim3(256), 0, stream,
                     xpb, Wpt, bp, xb, srcp, dstp, eattr, gcur, bspace,
                     E, NBK, gGemm, N);

  // bucket scan, then compact into exact CSR order
  hipLaunchKernelGGL(k_bscan, dim3(1), dim3(1024), 0, stream, gcur, boff, off, NBK, N);
  hipLaunchKernelGGL(k_p2, dim3(NBK), dim3(256), 0, stream, bspace, boff, gcur, ep, off, N);

  // ---- layer a: am = agg(xb); xb = mlp(am) + xb  (fused, in-place) ----
  hipLaunchKernelGGL(k_aggA, dim3(gAgg), dim3(256), 0, stream, xb, ep, off, embb, am, N);
  hipLaunchKernelGGL((k_mlpf<2>), dim3(gGemm), dim3(256), 0, stream,
                     am, W1at, b1a, W2at, b2a, xb, xb, N);

  // ---- layer b: am = agg(xb); d_out = mlp(am) + xb  (f32 out) ----
  hipLaunchKernelGGL(k_aggA, dim3(gAgg), dim3(256), 0, stream, xb, ep, off, embb, am, N);
  hipLaunchKernelGGL((k_mlpf<3>), dim3(gGemm), dim3(256), 0, stream,
                     am, W1bt, b1b, W2bt, b2b, xb, d_out, N);
}

// Round 19
// 334.065 us; speedup vs baseline: 1.1252x; 1.1125x over previous
//
#include <hip/hip_runtime.h>

typedef unsigned short u16;
typedef __attribute__((ext_vector_type(8))) short short8v;
typedef __attribute__((ext_vector_type(4))) float f32x4;

#define P1_CHUNK 8192
#define BKCAP    4096   // fixed bucket capacity: mean fill 2046, ~45-sigma margin

__device__ __forceinline__ u16 f2b(float f) {
  union { float fv; unsigned int i; } v; v.fv = f;
  unsigned int x = v.i;
  return (u16)((x + 0x7FFFu + ((x >> 16) & 1u)) >> 16);
}
__device__ __forceinline__ float bs2f(u16 u) {
  union { unsigned i; float f; } v; v.i = (unsigned)u << 16; return v.f;
}
__device__ __forceinline__ float blo(unsigned u) {
  union { unsigned i; float f; } v; v.i = u << 16; return v.f;
}
__device__ __forceinline__ float bhi(unsigned u) {
  union { unsigned i; float f; } v; v.i = u & 0xFFFF0000u; return v.f;
}

// ---------------- weight + emb prep + gcur zeroing (one launch, coalesced
// global writes -- round-14 lesson: no strided ds_write transposes) ----------
__global__ __launch_bounds__(256) void k_prepw_all(
    const float* __restrict__ Wp, const float* __restrict__ W1a,
    const float* __restrict__ W2a, const float* __restrict__ W1b,
    const float* __restrict__ W2b, const float* __restrict__ emb,
    u16* __restrict__ Wpt, u16* __restrict__ W1at, u16* __restrict__ W2at,
    u16* __restrict__ W1bt, u16* __restrict__ W2bt, u16* __restrict__ embb,
    int* __restrict__ gcur, int NBK)
{
  int idx = blockIdx.x * 256 + threadIdx.x;
  if (idx < 512 * 128) {
    int k = idx >> 7, c = idx & 127;
    Wpt[(size_t)c * 512 + k] = f2b(Wp[idx]);
    return;
  }
  idx -= 512 * 128;
  if (idx < 4 * 128 * 128) {
    int w = idx >> 14, r = idx & (128 * 128 - 1);
    int k = r >> 7, c = r & 127;
    const float* s = (w == 0) ? W1a : (w == 1) ? W2a : (w == 2) ? W1b : W2b;
    u16* d = (w == 0) ? W1at : (w == 1) ? W2at : (w == 2) ? W1bt : W2bt;
    d[(size_t)c * 128 + k] = f2b(s[r]);
    return;
  }
  idx -= 4 * 128 * 128;
  if (idx < 100 * 128) { embb[idx] = f2b(emb[idx]); return; }
  idx -= 100 * 128;
  if (idx < NBK) gcur[idx] = 0;   // re-zeroed every call (graph replay safe)
}

// ---------------- fused: proj (blocks < gProj) | p1 edge binning (rest) ------
// proj: xb = bf16(pept @ Wpt^T + bp), reads PRE-TRANSPOSED bf16 Wpt.
// NOTE: proj measured ~135us across 5 structural variants (LDS-A, direct-A,
// no-LDS, reg-prefetch, bf16-A) -- latency/concurrency plateau; this is the
// best-measured form (round 15, 337.7us total).
__global__ __launch_bounds__(256) void k_projp1(
    const float* __restrict__ A, const u16* __restrict__ Wt,
    const float* __restrict__ bias, u16* __restrict__ xb,
    const int* __restrict__ src, const int* __restrict__ dst,
    const int* __restrict__ attr, int* __restrict__ gcur,
    int* __restrict__ bspace, int nE, int NBK, int gProj, int N)
{
  __shared__ __align__(16) char smem[24576];   // proj: As 8KB + Bs 16KB; p1: lc 4KB
  const int t = threadIdx.x;

  if ((int)blockIdx.x < gProj) {
    u16* As = (u16*)smem;            // [64][64], row stride 128B, ^((r&7)<<4)
    u16* Bs = (u16*)(smem + 8192);   // [128][64], same swizzle
    const int row0 = blockIdx.x * 64;
    const int lane = t & 63;
    const int wave = t >> 6;
    const int wm = wave >> 1, wn = wave & 1;   // 2x2 waves: 32 rows x 64 cols
    const int colg = lane & 15, rowg = lane >> 4;

    f32x4 acc[2][4];
#pragma unroll
    for (int ni = 0; ni < 4; ++ni) {
      float bc = bias[wn * 64 + ni * 16 + colg];
#pragma unroll
      for (int mi = 0; mi < 2; ++mi) acc[mi][ni] = (f32x4){bc, bc, bc, bc};
    }

    for (int k0 = 0; k0 < 512; k0 += 64) {
#pragma unroll
      for (int i = 0; i < 4; ++i) {
        int idx = t + i * 256;            // 1024 float4 = 64 rows x 16
        int r = idx >> 4, kq = idx & 15;
        float4 v = make_float4(0.f, 0.f, 0.f, 0.f);
        if (row0 + r < N)
          v = *reinterpret_cast<const float4*>(A + (size_t)(row0 + r) * 512 + k0 + kq * 4);
        ushort4 b;
        b.x = f2b(v.x); b.y = f2b(v.y); b.z = f2b(v.z); b.w = f2b(v.w);
        int byteoff = (r * 128 + kq * 8) ^ ((r & 7) << 4);
        *reinterpret_cast<ushort4*>((char*)As + byteoff) = b;
      }
#pragma unroll
      for (int i = 0; i < 4; ++i) {
        int idx = t + i * 256;              // 1024 int4 = 128 cols x 8
        int c = idx >> 3, k8 = idx & 7;
        int4 v = *reinterpret_cast<const int4*>(Wt + (size_t)c * 512 + k0 + k8 * 8);
        int byteoff = (c * 128 + k8 * 16) ^ ((c & 7) << 4);
        *reinterpret_cast<int4*>((char*)Bs + byteoff) = v;
      }
      __syncthreads();
#pragma unroll
      for (int kk = 0; kk < 64; kk += 32) {
        short8v a[2], b[4];
#pragma unroll
        for (int mi = 0; mi < 2; ++mi) {
          int r = wm * 32 + mi * 16 + colg;
          int byteoff = (r * 128 + (kk + rowg * 8) * 2) ^ ((r & 7) << 4);
          a[mi] = *reinterpret_cast<const short8v*>((const char*)As + byteoff);
        }
#pragma unroll
        for (int ni = 0; ni < 4; ++ni) {
          int c = wn * 64 + ni * 16 + colg;
          int byteoff = (c * 128 + (kk + rowg * 8) * 2) ^ ((c & 7) << 4);
          b[ni] = *reinterpret_cast<const short8v*>((const char*)Bs + byteoff);
        }
#pragma unroll
        for (int mi = 0; mi < 2; ++mi)
#pragma unroll
          for (int ni = 0; ni < 4; ++ni)
            acc[mi][ni] = __builtin_amdgcn_mfma_f32_16x16x32_bf16(a[mi], b[ni], acc[mi][ni], 0, 0, 0);
      }
      __syncthreads();
    }

#pragma unroll
    for (int mi = 0; mi < 2; ++mi) {
#pragma unroll
      for (int j = 0; j < 4; ++j) {
        int row = row0 + wm * 32 + mi * 16 + rowg * 4 + j;
        if (row >= N) continue;
#pragma unroll
        for (int ni = 0; ni < 4; ++ni) {
          int col = wn * 64 + ni * 16 + colg;
          xb[(size_t)row * 128 + col] = f2b(acc[mi][ni][j]);
        }
      }
    }
  } else {
    // ---- p1: bin edges into 128-node dst-buckets ----
    int* lc = (int*)smem;             // NBK <= 1024
    const int bb = blockIdx.x - gProj;
    const int e0 = bb * P1_CHUNK;
    const int e1 = min(e0 + P1_CHUNK, nE);
    for (int i = t; i < NBK; i += 256) lc[i] = 0;
    __syncthreads();
    for (int e = e0 + t; e < e1; e += 256) atomicAdd(&lc[dst[e] >> 7], 1);
    __syncthreads();
    for (int i = t; i < NBK; i += 256) {
      int c = lc[i];
      if (c) lc[i] = atomicAdd(&gcur[i], c);   // bucket-local base
    }
    __syncthreads();
    for (int e = e0 + t; e < e1; e += 256) {
      int d = dst[e];
      int b = d >> 7;
      int pos = atomicAdd(&lc[b], 1);
      if (pos < BKCAP)
        bspace[(size_t)b * BKCAP + pos] = src[e] | (attr[e] << 17) | ((d & 127) << 24);
    }
  }
}

// phase 2: one block per bucket. Computes its OWN bucket prefix from bcnt
// (<=1024 coalesced reads + wave reduce -- replaces the k_bscan launch),
// derives per-node offsets, writes off[] AND the exactly-ordered ep[].
__global__ __launch_bounds__(256) void k_p2(
    const int* __restrict__ bspace, const int* __restrict__ bcnt,
    int* __restrict__ ep, int* __restrict__ off, int N, int NBK)
{
  __shared__ int cnt128[128];
  __shared__ int lc[128];
  __shared__ int wtot;
  __shared__ int red[4];
  const int b = blockIdx.x, t = threadIdx.x;
  const int lane = t & 63, wave = t >> 6;
  const int nb = b * 128;
  const int nn = min(128, N - nb);
  const size_t inbase = (size_t)b * BKCAP;
  const int ecnt = bcnt[b];

  // obase = sum_{j<b} bcnt[j]
  int partial = 0;
  for (int j = t; j < b; j += 256) partial += bcnt[j];
#pragma unroll
  for (int m = 32; m >= 1; m >>= 1) partial += __shfl_xor(partial, m);
  if (lane == 0) red[wave] = partial;
  if (t < 128) cnt128[t] = 0;
  __syncthreads();
  const int obase = red[0] + red[1] + red[2] + red[3];
  if (b == NBK - 1 && t == 0) off[N] = obase + ecnt;

  for (int i = t; i < ecnt; i += 256)
    atomicAdd(&cnt128[(bspace[inbase + i] >> 24) & 127], 1);
  __syncthreads();
  if (t < 128) {
    int v = cnt128[t];
    int s = v;
    for (int d = 1; d < 64; d <<= 1) { int u = __shfl_up(s, d); if (lane >= d) s += u; }
    if (t == 63) wtot = s;          // wave-0 total
    __syncthreads();
    int excl = s - v + ((t >= 64) ? wtot : 0);
    int start = obase + excl;
    lc[t] = start;
    if (t < nn) off[nb + t] = start;
  } else {
    __syncthreads();
  }
  __syncthreads();
  for (int i = t; i < ecnt; i += 256) {
    int p = bspace[inbase + i];
    int pos = atomicAdd(&lc[(p >> 24) & 127], 1);
    ep[pos] = p & 0xFFFFFF;
  }
}

// am[i] = bf16( xb[i] + sum_{e in-edges(i)} relu(xb[src]+embb[attr]) )
// one wave/node; unroll-8 gather (16 loads in flight), split accumulators
__global__ __launch_bounds__(256) void k_aggA(
    const u16* __restrict__ xb, const int* __restrict__ ep,
    const int* __restrict__ off, const u16* __restrict__ embb,
    u16* __restrict__ am, int N)
{
  const int node = blockIdx.x * 4 + (threadIdx.x >> 6);
  if (node >= N) return;
  const int lane = threadIdx.x & 63;
  const int beg = off[node], end = off[node + 1];
  float ax0 = 0.f, ay0 = 0.f, ax1 = 0.f, ay1 = 0.f;
  int e = beg;
  for (; e + 8 <= end; e += 8) {
    int pp[8];
#pragma unroll
    for (int j = 0; j < 8; ++j) pp[j] = ep[e + j];
    unsigned xu[8], eu[8];
#pragma unroll
    for (int j = 0; j < 8; ++j) {
      xu[j] = *reinterpret_cast<const unsigned*>(xb + ((size_t)(pp[j] & 0x1FFFF) << 7) + lane * 2);
      eu[j] = *reinterpret_cast<const unsigned*>(embb + ((size_t)(pp[j] >> 17) << 7) + lane * 2);
    }
#pragma unroll
    for (int j = 0; j < 8; j += 2) {
      ax0 += fmaxf(blo(xu[j]) + blo(eu[j]), 0.f);
      ay0 += fmaxf(bhi(xu[j]) + bhi(eu[j]), 0.f);
      ax1 += fmaxf(blo(xu[j + 1]) + blo(eu[j + 1]), 0.f);
      ay1 += fmaxf(bhi(xu[j + 1]) + bhi(eu[j + 1]), 0.f);
    }
  }
  for (; e < end; ++e) {
    int p = ep[e];
    unsigned xu = *reinterpret_cast<const unsigned*>(xb + ((size_t)(p & 0x1FFFF) << 7) + lane * 2);
    unsigned eu = *reinterpret_cast<const unsigned*>(embb + ((size_t)(p >> 17) << 7) + lane * 2);
    ax0 += fmaxf(blo(xu) + blo(eu), 0.f);
    ay0 += fmaxf(bhi(xu) + bhi(eu), 0.f);
  }
  unsigned xo = *reinterpret_cast<const unsigned*>(xb + ((size_t)node << 7) + lane * 2);
  float ax = ax0 + ax1 + blo(xo);
  float ay = ay0 + ay1 + bhi(xo);
  unsigned w = ((unsigned)f2b(ay) << 16) | (unsigned)f2b(ax);
  *reinterpret_cast<unsigned*>(am + ((size_t)node << 7) + lane * 2) = w;
}

// ---------------- fused MLP: out = relu(am@W1+b1)@W2 + b2 + res ----------------
// EPI2: 2 = +res -> bf16 out (in-place xb safe), 3 = +res -> f32 out
template <int EPI2>
__global__ __launch_bounds__(256) void k_mlpf(
    const u16* __restrict__ am, const u16* __restrict__ W1t,
    const float* __restrict__ b1, const u16* __restrict__ W2t,
    const float* __restrict__ b2, const u16* __restrict__ resb,
    void* __restrict__ outp, int N)
{
  __shared__ u16 As[64 * 128];   // 16KB: am tile, then h (row stride 256B)
  __shared__ u16 Bs[128 * 128];  // 32KB: W1, then W2
  const int t = threadIdx.x;
  const int row0 = blockIdx.x * 64;
  const int lane = t & 63, wave = t >> 6;
  const int wm = wave >> 1, wn = wave & 1;   // 2x2 waves: 32 rows x 64 cols
  const int colg = lane & 15, rowg = lane >> 4;

#pragma unroll
  for (int i = 0; i < 4; ++i) {
    int idx = t + i * 256, r = idx >> 4, k8 = idx & 15;
    int4 v = make_int4(0, 0, 0, 0);
    if (row0 + r < N)
      v = *reinterpret_cast<const int4*>(am + (size_t)(row0 + r) * 128 + k8 * 8);
    int byteoff = (r * 256 + k8 * 16) ^ ((r & 7) << 4);
    *reinterpret_cast<int4*>((char*)As + byteoff) = v;
  }
#pragma unroll
  for (int i = 0; i < 8; ++i) {
    int idx = t + i * 256, c = idx >> 4, k8 = idx & 15;
    int4 v = *reinterpret_cast<const int4*>(W1t + (size_t)c * 128 + k8 * 8);
    int byteoff = (c * 256 + k8 * 16) ^ ((c & 7) << 4);
    *reinterpret_cast<int4*>((char*)Bs + byteoff) = v;
  }
  __syncthreads();

  f32x4 acc[2][4];
#pragma unroll
  for (int ni = 0; ni < 4; ++ni) {
    float bc = b1[wn * 64 + ni * 16 + colg];
#pragma unroll
    for (int mi = 0; mi < 2; ++mi) acc[mi][ni] = (f32x4){bc, bc, bc, bc};
  }
#pragma unroll
  for (int kk = 0; kk < 128; kk += 32) {
    short8v a[2], b[4];
#pragma unroll
    for (int mi = 0; mi < 2; ++mi) {
      int r = wm * 32 + mi * 16 + colg;
      int byteoff = (r * 256 + (kk + rowg * 8) * 2) ^ ((r & 7) << 4);
      a[mi] = *reinterpret_cast<const short8v*>((const char*)As + byteoff);
    }
#pragma unroll
    for (int ni = 0; ni < 4; ++ni) {
      int c = wn * 64 + ni * 16 + colg;
      int byteoff = (c * 256 + (kk + rowg * 8) * 2) ^ ((c & 7) << 4);
      b[ni] = *reinterpret_cast<const short8v*>((const char*)Bs + byteoff);
    }
#pragma unroll
    for (int mi = 0; mi < 2; ++mi)
#pragma unroll
      for (int ni = 0; ni < 4; ++ni)
        acc[mi][ni] = __builtin_amdgcn_mfma_f32_16x16x32_bf16(a[mi], b[ni], acc[mi][ni], 0, 0, 0);
  }
  __syncthreads();   // all As/Bs reads complete before overwrite

  // h = relu(acc) -> As (bf16), stage W2 -> Bs
#pragma unroll
  for (int mi = 0; mi < 2; ++mi) {
#pragma unroll
    for (int j = 0; j < 4; ++j) {
      int row = wm * 32 + mi * 16 + rowg * 4 + j;
#pragma unroll
      for (int ni = 0; ni < 4; ++ni) {
        int col = wn * 64 + ni * 16 + colg;
        int byteoff = (row * 256 + col * 2) ^ ((row & 7) << 4);
        *reinterpret_cast<u16*>((char*)As + byteoff) = f2b(fmaxf(acc[mi][ni][j], 0.f));
      }
    }
  }
#pragma unroll
  for (int i = 0; i < 8; ++i) {
    int idx = t + i * 256, c = idx >> 4, k8 = idx & 15;
    int4 v = *reinterpret_cast<const int4*>(W2t + (size_t)c * 128 + k8 * 8);
    int byteoff = (c * 256 + k8 * 16) ^ ((c & 7) << 4);
    *reinterpret_cast<int4*>((char*)Bs + byteoff) = v;
  }
  __syncthreads();

#pragma unroll
  for (int ni = 0; ni < 4; ++ni) {
    float bc = b2[wn * 64 + ni * 16 + colg];
#pragma unroll
    for (int mi = 0; mi < 2; ++mi) acc[mi][ni] = (f32x4){bc, bc, bc, bc};
  }
#pragma unroll
  for (int kk = 0; kk < 128; kk += 32) {
    short8v a[2], b[4];
#pragma unroll
    for (int mi = 0; mi < 2; ++mi) {
      int r = wm * 32 + mi * 16 + colg;
      int byteoff = (r * 256 + (kk + rowg * 8) * 2) ^ ((r & 7) << 4);
      a[mi] = *reinterpret_cast<const short8v*>((const char*)As + byteoff);
    }
#pragma unroll
    for (int ni = 0; ni < 4; ++ni) {
      int c = wn * 64 + ni * 16 + colg;
      int byteoff = (c * 256 + (kk + rowg * 8) * 2) ^ ((c & 7) << 4);
      b[ni] = *reinterpret_cast<const short8v*>((const char*)Bs + byteoff);
    }
#pragma unroll
    for (int mi = 0; mi < 2; ++mi)
#pragma unroll
      for (int ni = 0; ni < 4; ++ni)
        acc[mi][ni] = __builtin_amdgcn_mfma_f32_16x16x32_bf16(a[mi], b[ni], acc[mi][ni], 0, 0, 0);
  }

#pragma unroll
  for (int mi = 0; mi < 2; ++mi) {
#pragma unroll
    for (int j = 0; j < 4; ++j) {
      int row = row0 + wm * 32 + mi * 16 + rowg * 4 + j;
      if (row >= N) continue;
#pragma unroll
      for (int ni = 0; ni < 4; ++ni) {
        int col = wn * 64 + ni * 16 + colg;
        float v = acc[mi][ni][j] + bs2f(resb[(size_t)row * 128 + col]);
        if (EPI2 == 2) ((u16*)outp)[(size_t)row * 128 + col] = f2b(v);
        else           ((float*)outp)[(size_t)row * 128 + col] = v;
      }
    }
  }
}

// ---------------- launcher ----------------
extern "C" void kernel_launch(void* const* d_in, const int* in_sizes, int n_in,
                              void* d_out, int out_size, void* d_ws, size_t ws_size,
                              hipStream_t stream)
{
  const float* pept  = (const float*)d_in[0];
  const int*   eidx  = (const int*)d_in[1];
  const int*   eattr = (const int*)d_in[2];
  const float* Wp  = (const float*)d_in[3];
  const float* bp  = (const float*)d_in[4];
  const float* emb = (const float*)d_in[5];
  // d_in[6]=cls_token, d_in[7]=cls_edge: dead for the output (CLS node is never
  // a source and row N is dropped) -> skipped.
  const float* W1a = (const float*)d_in[8];
  const float* b1a = (const float*)d_in[9];
  const float* W2a = (const float*)d_in[10];
  const float* b2a = (const float*)d_in[11];
  const float* W1b = (const float*)d_in[12];
  const float* b1b = (const float*)d_in[13];
  const float* W2b = (const float*)d_in[14];
  const float* b2b = (const float*)d_in[15];

  const int N = in_sizes[0] / 512;
  const int E = in_sizes[1] / 2;
  const int* srcp = eidx;
  const int* dstp = eidx + E;
  const int NBK = (N + 127) / 128;       // dst buckets

  char* ws = (char*)d_ws;
  char* p = ws;
  u16* xb  = (u16*)p;               p += (size_t)N * 128 * 2;   // bf16 x master
  u16* am  = (u16*)p;               p += (size_t)N * 128 * 2;   // bf16 A for MLP
  int* off    = (int*)p;            p += (size_t)(N + 1) * 4;
  int* gcur   = (int*)p;            p += (size_t)NBK * 4;
  int* ep     = (int*)p;            p += (size_t)E * 4;
  int* bspace = (int*)p;            p += (size_t)NBK * BKCAP * 4;
  u16* Wpt  = (u16*)p;              p += (size_t)512 * 128 * 2;
  u16* W1at = (u16*)p;              p += (size_t)128 * 128 * 2;
  u16* W2at = (u16*)p;              p += (size_t)128 * 128 * 2;
  u16* W1bt = (u16*)p;              p += (size_t)128 * 128 * 2;
  u16* W2bt = (u16*)p;              p += (size_t)128 * 128 * 2;
  u16* embb = (u16*)p;              p += (size_t)100 * 128 * 2;

  const int gGemm = (N + 63) / 64;
  const int gAgg  = (N + 3) / 4;
  const int gP1   = (E + P1_CHUNK - 1) / P1_CHUNK;
  const int gPrep = (512 * 128 + 4 * 128 * 128 + 100 * 128 + 1024 + 255) / 256;

  // prep: all weight transposes via coalesced global writes + gcur zeroing
  hipLaunchKernelGGL(k_prepw_all, dim3(gPrep), dim3(256), 0, stream,
                     Wp, W1a, W2a, W1b, W2b, emb,
                     Wpt, W1at, W2at, W1bt, W2bt, embb, gcur, NBK);

  // proj (MFMA, LDS-staged) overlapped with p1 edge binning
  hipLaunchKernelGGL(k_projp1, dim3(gGemm + gP1), dim3(256), 0, stream,
                     pept, Wpt, bp, xb, srcp, dstp, eattr, gcur, bspace,
                     E, NBK, gGemm, N);

  // compact into exact CSR order (each block derives its own bucket prefix)
  hipLaunchKernelGGL(k_p2, dim3(NBK), dim3(256), 0, stream,
                     bspace, gcur, ep, off, N, NBK);

  // ---- layer a: am = agg(xb); xb = mlp(am) + xb  (fused, in-place) ----
  hipLaunchKernelGGL(k_aggA, dim3(gAgg), dim3(256), 0, stream, xb, ep, off, embb, am, N);
  hipLaunchKernelGGL((k_mlpf<2>), dim3(gGemm), dim3(256), 0, stream,
                     am, W1at, b1a, W2at, b2a, xb, xb, N);

  // ---- layer b: am = agg(xb); d_out = mlp(am) + xb  (f32 out) ----
  hipLaunchKernelGGL(k_aggA, dim3(gAgg), dim3(256), 0, stream, xb, ep, off, embb, am, N);
  hipLaunchKernelGGL((k_mlpf<3>), dim3(gGemm), dim3(256), 0, stream,
                     am, W1bt, b1b, W2bt, b2b, xb, d_out, N);
}